// Round 7
// baseline (296.078 us; speedup 1.0000x reference)
//
#include <hip/hip_runtime.h>

#define T_ 2048
#define H_ 1024
#define E_ 8
#define I_ 2048

typedef short bf16x8 __attribute__((ext_vector_type(8)));
typedef float f32x4 __attribute__((ext_vector_type(4)));
typedef unsigned short u16x8 __attribute__((ext_vector_type(8)));

__device__ __forceinline__ unsigned short f2bf(float f) {
  unsigned u = __builtin_bit_cast(unsigned, f);
  u += 0x7fffu + ((u >> 16) & 1u);   // RNE (finite inputs only)
  return (unsigned short)(u >> 16);
}

#define GLOAD_LDS16(g, l)                                                     \
  __builtin_amdgcn_global_load_lds(                                           \
      (const __attribute__((address_space(1))) unsigned int*)(g),             \
      (__attribute__((address_space(3))) unsigned int*)(l), 16, 0, 0)

// ---------------- fp32 -> bf16 linear convert (hs only) --------------------
__global__ __launch_bounds__(256) void cvt_kernel(const float* __restrict__ s,
                                                  unsigned short* __restrict__ d,
                                                  int n8) {
  int i = blockIdx.x * blockDim.x + threadIdx.x;
  if (i >= n8) return;
  const float4* s4 = (const float4*)s;
  float4 a = s4[2 * i], b = s4[2 * i + 1];
  u16x8 v;
  v[0] = f2bf(a.x); v[1] = f2bf(a.y); v[2] = f2bf(a.z); v[3] = f2bf(a.w);
  v[4] = f2bf(b.x); v[5] = f2bf(b.y); v[6] = f2bf(b.z); v[7] = f2bf(b.w);
  *(u16x8*)(d + (size_t)i * 8) = v;
}

// ---------------- router: softmax + top2 + expert compaction ----------------
__global__ void router_kernel(const float* __restrict__ logits,
                              int* __restrict__ cnt,
                              int* __restrict__ plist,
                              float* __restrict__ wlist) {
  int t = blockIdx.x * blockDim.x + threadIdx.x;
  if (t >= T_) return;
  float l[E_];
#pragma unroll
  for (int e = 0; e < E_; ++e) l[e] = logits[t * E_ + e];
  int i0 = 0;
#pragma unroll
  for (int e = 1; e < E_; ++e) if (l[e] > l[i0]) i0 = e;
  int i1 = (i0 == 0) ? 1 : 0;
#pragma unroll
  for (int e = 0; e < E_; ++e) if (e != i0 && l[e] > l[i1]) i1 = e;
  float w1 = 1.f / (1.f + __expf(l[i0] - l[i1]));
  float w0 = 1.f - w1;
  int s0 = atomicAdd(&cnt[i0], 1);
  plist[i0 * T_ + s0] = 2 * t;
  wlist[i0 * T_ + s0] = w0;
  int s1 = atomicAdd(&cnt[i1], 1);
  plist[i1 * T_ + s1] = 2 * t + 1;
  wlist[i1 * T_ + s1] = w1;
}

// ---------------- GEMM1: act = silu(hs*w13_g)*(hs*w13_u)*w ------------------
// BM=128, BN=64 i-cols (gate+up => 128 B rows), BK=32, 4 waves.
// A: bf16 gload_lds dbuf; B: fp32 reg-staged 2-DEEP pipeline, counted vmcnt.
__global__ __launch_bounds__(256, 4) void gemm1_kernel(
    const unsigned short* __restrict__ hs_bf,
    const float* __restrict__ w13,
    const int* __restrict__ cnt, const int* __restrict__ plist,
    const float* __restrict__ wlist, unsigned short* __restrict__ act) {
  const int bid = blockIdx.x;
  const int e = bid & 7;
  const int mt = (bid >> 3) & 15;
  const int nt = bid >> 7;                 // 0..31
  const int M = cnt[e];
  if (mt * 128 >= M) return;
  const int Mrem = M - mt * 128;
  const int n0 = nt * 64;
  const int NT = 32;

  __shared__ __align__(16) unsigned short As[2][128][32];
  __shared__ __align__(16) unsigned short Bs[128][32];

  const int tid = threadIdx.x;
  const int lane = tid & 63;
  const int wid = tid >> 6;
  const int wm = (wid >> 1) * 64;
  const int wn = (wid & 1) * 32;

  const unsigned short* aSrc0;
  const unsigned short* aSrc1;
  {
    int cg = ((lane & 3) ^ ((lane >> 3) & 3)) * 8;
#pragma unroll
    for (int i = 0; i < 2; ++i) {
      int r = wid * 32 + i * 16 + (lane >> 2);
      int idx = mt * 128 + ((r < Mrem) ? r : 0);
      int p = plist[e * T_ + idx];
      const unsigned short* s = hs_bf + (size_t)(p >> 1) * H_ + cg;
      if (i == 0) aSrc0 = s; else aSrc1 = s;
    }
  }
  const int rb = wid * 32 + (lane >> 1);
  const int wrow = (rb < 64) ? (e * 2 * I_ + n0 + rb)
                             : (e * 2 * I_ + I_ + n0 + (rb - 64));
  const float* bSrc = w13 + (size_t)wrow * H_ + (lane & 1) * 16;
  const int fb = (rb >> 1) & 3;
  unsigned short* bDst0 = &Bs[rb][((((lane & 1) << 1) | 0) ^ fb) * 8];
  unsigned short* bDst1 = &Bs[rb][((((lane & 1) << 1) | 1) ^ fb) * 8];

  const int rda = ((lane >> 4) ^ ((lane >> 1) & 3)) * 8;  // frag col (A & B)
  const int l15 = lane & 15;

  f32x4 accg[4][2] = {};
  f32x4 accu[4][2] = {};

  // 2-deep B pipeline registers
  float4 bset[2][4];

  // prologue: Breg(0)->set0, A(0), Breg(1)->set1
#pragma unroll
  for (int j = 0; j < 4; ++j) bset[0][j] = *(const float4*)(bSrc + j * 4);
  GLOAD_LDS16(aSrc0, &As[0][wid * 32][0]);
  GLOAD_LDS16(aSrc1, &As[0][wid * 32 + 16][0]);
#pragma unroll
  for (int j = 0; j < 4; ++j) bset[1][j] = *(const float4*)(bSrc + 32 + j * 4);

#pragma unroll 2
  for (int kt = 0; kt < NT; ++kt) {
    const int s = kt & 1;
    // W1: wait Breg(kt). queue: Breg(kt)(4), A(kt)(2), Breg(kt+1)(4)
    if (kt + 1 < NT) asm volatile("s_waitcnt vmcnt(6)" ::: "memory");
    else             asm volatile("s_waitcnt vmcnt(2)" ::: "memory");
    {
      u16x8 lo, hi;
      lo[0] = f2bf(bset[s][0].x); lo[1] = f2bf(bset[s][0].y);
      lo[2] = f2bf(bset[s][0].z); lo[3] = f2bf(bset[s][0].w);
      lo[4] = f2bf(bset[s][1].x); lo[5] = f2bf(bset[s][1].y);
      lo[6] = f2bf(bset[s][1].z); lo[7] = f2bf(bset[s][1].w);
      hi[0] = f2bf(bset[s][2].x); hi[1] = f2bf(bset[s][2].y);
      hi[2] = f2bf(bset[s][2].z); hi[3] = f2bf(bset[s][2].w);
      hi[4] = f2bf(bset[s][3].x); hi[5] = f2bf(bset[s][3].y);
      hi[6] = f2bf(bset[s][3].z); hi[7] = f2bf(bset[s][3].w);
      *(u16x8*)bDst0 = lo;
      *(u16x8*)bDst1 = hi;
    }
    if (kt + 1 < NT) {
      GLOAD_LDS16(aSrc0 + (kt + 1) * 32, &As[s ^ 1][wid * 32][0]);
      GLOAD_LDS16(aSrc1 + (kt + 1) * 32, &As[s ^ 1][wid * 32 + 16][0]);
    }
    if (kt + 2 < NT) {
#pragma unroll
      for (int j = 0; j < 4; ++j)
        bset[s][j] = *(const float4*)(bSrc + (kt + 2) * 32 + j * 4);
    }
    // W2: wait A(kt).
    if (kt + 2 < NT)      asm volatile("s_waitcnt vmcnt(10)" ::: "memory");
    else if (kt + 1 < NT) asm volatile("s_waitcnt vmcnt(6)" ::: "memory");
    else                  asm volatile("s_waitcnt vmcnt(0)" ::: "memory");
    asm volatile("s_waitcnt lgkmcnt(0)" ::: "memory");
    __builtin_amdgcn_s_barrier();
    __builtin_amdgcn_sched_barrier(0);

    bf16x8 bg[2], bu[2];
#pragma unroll
    for (int ni = 0; ni < 2; ++ni) {
      bg[ni] = *(const bf16x8*)&Bs[wn + ni * 16 + l15][rda];
      bu[ni] = *(const bf16x8*)&Bs[64 + wn + ni * 16 + l15][rda];
    }
#pragma unroll
    for (int mi = 0; mi < 4; ++mi) {
      bf16x8 af = *(const bf16x8*)&As[s][wm + mi * 16 + l15][rda];
#pragma unroll
      for (int ni = 0; ni < 2; ++ni) {
        accg[mi][ni] = __builtin_amdgcn_mfma_f32_16x16x32_bf16(af, bg[ni], accg[mi][ni], 0, 0, 0);
        accu[mi][ni] = __builtin_amdgcn_mfma_f32_16x16x32_bf16(af, bu[ni], accu[mi][ni], 0, 0, 0);
      }
    }
    __builtin_amdgcn_sched_barrier(0);
    __builtin_amdgcn_s_barrier();
  }

  const int lrow = lane >> 4, lcol = lane & 15;
#pragma unroll
  for (int mi = 0; mi < 4; ++mi) {
#pragma unroll
    for (int r = 0; r < 4; ++r) {
      int rl = wm + mi * 16 + lrow * 4 + r;
      if (rl < Mrem) {
        int rr = mt * 128 + rl;
        int p = plist[e * T_ + rr];
        float w = wlist[e * T_ + rr];
        unsigned short* dst = act + (size_t)p * I_ + n0;
#pragma unroll
        for (int ni = 0; ni < 2; ++ni) {
          float g = accg[mi][ni][r];
          float u = accu[mi][ni][r];
          float a = (g / (1.f + __expf(-g))) * u * w;
          dst[wn + ni * 16 + lcol] = f2bf(a);
        }
      }
    }
  }
}

// ---------------- GEMM2: part[kb][p][h] = act[p,k0:k0+512].w2[e,h,k0:k0+512]
// BM=128, BN=128 h-cols, BK=32, K-split x4, NO atomics (partial buffers).
__global__ __launch_bounds__(256, 4) void gemm2_kernel(
    const unsigned short* __restrict__ act,
    const float* __restrict__ w2,
    const int* __restrict__ cnt, const int* __restrict__ plist,
    float* __restrict__ part) {
  const int bid = blockIdx.x;
  const int e = bid & 7;
  const int mt = (bid >> 3) & 15;
  const int nt = (bid >> 7) & 7;
  const int kb = bid >> 10;                // 0..3, K chunk of 512
  const int M = cnt[e];
  if (mt * 128 >= M) return;
  const int Mrem = M - mt * 128;
  const int n0 = nt * 128;
  const int k0 = kb * 512;

  __shared__ __align__(16) unsigned short As[2][128][32];
  __shared__ __align__(16) unsigned short Bs[128][32];

  const int tid = threadIdx.x;
  const int lane = tid & 63;
  const int wid = tid >> 6;
  const int wm = (wid >> 1) * 64;
  const int wn = (wid & 1) * 64;

  const unsigned short* aSrc0;
  const unsigned short* aSrc1;
  {
    int cg = ((lane & 3) ^ ((lane >> 3) & 3)) * 8;
#pragma unroll
    for (int i = 0; i < 2; ++i) {
      int r = wid * 32 + i * 16 + (lane >> 2);
      int idx = mt * 128 + ((r < Mrem) ? r : 0);
      int p = plist[e * T_ + idx];
      const unsigned short* s = act + (size_t)p * I_ + k0 + cg;
      if (i == 0) aSrc0 = s; else aSrc1 = s;
    }
  }
  const int rb = wid * 32 + (lane >> 1);
  const float* bSrc = w2 + ((size_t)e * H_ + n0 + rb) * I_ + k0 + (lane & 1) * 16;
  const int fb = (rb >> 1) & 3;
  unsigned short* bDst0 = &Bs[rb][((((lane & 1) << 1) | 0) ^ fb) * 8];
  unsigned short* bDst1 = &Bs[rb][((((lane & 1) << 1) | 1) ^ fb) * 8];

  const int rda = ((lane >> 4) ^ ((lane >> 1) & 3)) * 8;
  const int l15 = lane & 15;

  f32x4 acc[4][4] = {};

  GLOAD_LDS16(aSrc0, &As[0][wid * 32][0]);
  GLOAD_LDS16(aSrc1, &As[0][wid * 32 + 16][0]);
  float4 b0 = *(const float4*)(bSrc + 0);
  float4 b1 = *(const float4*)(bSrc + 4);
  float4 b2 = *(const float4*)(bSrc + 8);
  float4 b3 = *(const float4*)(bSrc + 12);

#pragma unroll 1
  for (int kt = 0; kt < 16; ++kt) {
    const int cur = kt & 1;
    asm volatile("s_waitcnt vmcnt(0)" ::: "memory");
    {
      u16x8 lo, hi;
      lo[0] = f2bf(b0.x); lo[1] = f2bf(b0.y); lo[2] = f2bf(b0.z); lo[3] = f2bf(b0.w);
      lo[4] = f2bf(b1.x); lo[5] = f2bf(b1.y); lo[6] = f2bf(b1.z); lo[7] = f2bf(b1.w);
      hi[0] = f2bf(b2.x); hi[1] = f2bf(b2.y); hi[2] = f2bf(b2.z); hi[3] = f2bf(b2.w);
      hi[4] = f2bf(b3.x); hi[5] = f2bf(b3.y); hi[6] = f2bf(b3.z); hi[7] = f2bf(b3.w);
      *(u16x8*)bDst0 = lo;
      *(u16x8*)bDst1 = hi;
    }
    if (kt + 1 < 16) {
      GLOAD_LDS16(aSrc0 + (kt + 1) * 32, &As[cur ^ 1][wid * 32][0]);
      GLOAD_LDS16(aSrc1 + (kt + 1) * 32, &As[cur ^ 1][wid * 32 + 16][0]);
      b0 = *(const float4*)(bSrc + (kt + 1) * 32 + 0);
      b1 = *(const float4*)(bSrc + (kt + 1) * 32 + 4);
      b2 = *(const float4*)(bSrc + (kt + 1) * 32 + 8);
      b3 = *(const float4*)(bSrc + (kt + 1) * 32 + 12);
    }
    asm volatile("s_waitcnt lgkmcnt(0)" ::: "memory");
    __builtin_amdgcn_s_barrier();
    __builtin_amdgcn_sched_barrier(0);

    bf16x8 bb[4];
#pragma unroll
    for (int ni = 0; ni < 4; ++ni)
      bb[ni] = *(const bf16x8*)&Bs[wn + ni * 16 + l15][rda];
#pragma unroll
    for (int mi = 0; mi < 4; ++mi) {
      bf16x8 af = *(const bf16x8*)&As[cur][wm + mi * 16 + l15][rda];
#pragma unroll
      for (int ni = 0; ni < 4; ++ni)
        acc[mi][ni] = __builtin_amdgcn_mfma_f32_16x16x32_bf16(af, bb[ni], acc[mi][ni], 0, 0, 0);
    }
    __builtin_amdgcn_sched_barrier(0);
    __builtin_amdgcn_s_barrier();
  }

  const int lrow = lane >> 4, lcol = lane & 15;
#pragma unroll
  for (int mi = 0; mi < 4; ++mi) {
#pragma unroll
    for (int r = 0; r < 4; ++r) {
      int rl = wm + mi * 16 + lrow * 4 + r;
      if (rl < Mrem) {
        int p = plist[e * T_ + mt * 128 + rl];
#pragma unroll
        for (int ni = 0; ni < 4; ++ni)
          part[((size_t)kb * 2 * T_ + p) * H_ + n0 + wn + ni * 16 + lcol] =
              acc[mi][ni][r];
      }
    }
  }
}

// ---------------- reduce: out[t,h] = sum_kb sum_pp part[kb][2t+pp][h] -------
__global__ __launch_bounds__(256) void reduce_kernel(const float* __restrict__ part,
                                                     float* __restrict__ out) {
  int i = blockIdx.x * blockDim.x + threadIdx.x;   // over T_*H_/4
  int t = i >> 8;                                  // H_/4 = 256
  int c = (i & 255) << 2;
  f32x4 s = {0.f, 0.f, 0.f, 0.f};
#pragma unroll
  for (int kb = 0; kb < 4; ++kb) {
#pragma unroll
    for (int pp = 0; pp < 2; ++pp) {
      f32x4 v = *(const f32x4*)(part + ((size_t)kb * 2 * T_ + 2 * t + pp) * H_ + c);
      s += v;
    }
  }
  *(f32x4*)(out + (size_t)t * H_ + c) = s;
}

extern "C" void kernel_launch(void* const* d_in, const int* in_sizes, int n_in,
                              void* d_out, int out_size, void* d_ws, size_t ws_size,
                              hipStream_t stream) {
  const float* hs     = (const float*)d_in[0];
  const float* logits = (const float*)d_in[1];
  const float* w13    = (const float*)d_in[2];
  const float* w2     = (const float*)d_in[3];
  float* out = (float*)d_out;

  char* ws = (char*)d_ws;
  size_t off = 0;
  int* cnt = (int*)(ws + off);           off += 256;
  int* plist = (int*)(ws + off);         off += (size_t)E_ * T_ * 4;
  float* wlist = (float*)(ws + off);     off += (size_t)E_ * T_ * 4;
  unsigned short* act = (unsigned short*)(ws + off);   off += (size_t)2 * T_ * I_ * 2;
  unsigned short* hs_bf = (unsigned short*)(ws + off); off += (size_t)T_ * H_ * 2;
  float* part = (float*)(ws + off);      off += (size_t)4 * 2 * T_ * H_ * 4;
  // total ~84 MB

  hipMemsetAsync(cnt, 0, 256, stream);

  const int nHs = T_ * H_ / 8;
  cvt_kernel<<<(nHs + 255) / 256, 256, 0, stream>>>(hs, hs_bf, nHs);
  router_kernel<<<T_ / 256, 256, 0, stream>>>(logits, cnt, plist, wlist);

  gemm1_kernel<<<E_ * 16 * 32, 256, 0, stream>>>(hs_bf, w13, cnt, plist, wlist, act);
  gemm2_kernel<<<E_ * 16 * 8 * 4, 256, 0, stream>>>(act, w2, cnt, plist, part);
  reduce_kernel<<<T_ * H_ / 4 / 256, 256, 0, stream>>>(part, out);
}

// Round 8
// 265.692 us; speedup vs baseline: 1.1144x; 1.1144x over previous
//
#include <hip/hip_runtime.h>

#define T_ 2048
#define H_ 1024
#define E_ 8
#define I_ 2048

typedef short bf16x8 __attribute__((ext_vector_type(8)));
typedef float f32x4 __attribute__((ext_vector_type(4)));
typedef unsigned short u16x8 __attribute__((ext_vector_type(8)));

__device__ __forceinline__ unsigned short f2bf(float f) {
  unsigned u = __builtin_bit_cast(unsigned, f);
  u += 0x7fffu + ((u >> 16) & 1u);   // RNE (finite inputs only)
  return (unsigned short)(u >> 16);
}

#define GLOAD_LDS16(g, l)                                                     \
  __builtin_amdgcn_global_load_lds(                                           \
      (const __attribute__((address_space(1))) unsigned int*)(g),             \
      (__attribute__((address_space(3))) unsigned int*)(l), 16, 0, 0)

// ---------------- fp32 -> bf16 linear convert (hs only) --------------------
__global__ __launch_bounds__(256) void cvt_kernel(const float* __restrict__ s,
                                                  unsigned short* __restrict__ d,
                                                  int n8) {
  int i = blockIdx.x * blockDim.x + threadIdx.x;
  if (i >= n8) return;
  const float4* s4 = (const float4*)s;
  float4 a = s4[2 * i], b = s4[2 * i + 1];
  u16x8 v;
  v[0] = f2bf(a.x); v[1] = f2bf(a.y); v[2] = f2bf(a.z); v[3] = f2bf(a.w);
  v[4] = f2bf(b.x); v[5] = f2bf(b.y); v[6] = f2bf(b.z); v[7] = f2bf(b.w);
  *(u16x8*)(d + (size_t)i * 8) = v;
}

// ---------------- router: softmax + top2 + expert compaction ----------------
__global__ void router_kernel(const float* __restrict__ logits,
                              int* __restrict__ cnt,
                              int* __restrict__ plist,
                              float* __restrict__ wlist) {
  int t = blockIdx.x * blockDim.x + threadIdx.x;
  if (t >= T_) return;
  float l[E_];
#pragma unroll
  for (int e = 0; e < E_; ++e) l[e] = logits[t * E_ + e];
  int i0 = 0;
#pragma unroll
  for (int e = 1; e < E_; ++e) if (l[e] > l[i0]) i0 = e;
  int i1 = (i0 == 0) ? 1 : 0;
#pragma unroll
  for (int e = 0; e < E_; ++e) if (e != i0 && l[e] > l[i1]) i1 = e;
  float w1 = 1.f / (1.f + __expf(l[i0] - l[i1]));
  float w0 = 1.f - w1;
  int s0 = atomicAdd(&cnt[i0], 1);
  plist[i0 * T_ + s0] = 2 * t;
  wlist[i0 * T_ + s0] = w0;
  int s1 = atomicAdd(&cnt[i1], 1);
  plist[i1 * T_ + s1] = 2 * t + 1;
  wlist[i1 * T_ + s1] = w1;
}

// ---------------- GEMM1: act = silu(hs*w13_g)*(hs*w13_u)*w ------------------
// BM=128, BN=64 i-cols (gate+up => 128 B rows), BK=32, 4 waves.
// A: bf16 gload_lds dbuf; B: fp32 reg-staged 2-DEEP pipeline, counted vmcnt.
__global__ __launch_bounds__(256, 4) void gemm1_kernel(
    const unsigned short* __restrict__ hs_bf,
    const float* __restrict__ w13,
    const int* __restrict__ cnt, const int* __restrict__ plist,
    const float* __restrict__ wlist, unsigned short* __restrict__ act) {
  const int bid = blockIdx.x;
  const int e = bid & 7;
  const int mt = (bid >> 3) & 15;
  const int nt = bid >> 7;                 // 0..31
  const int M = cnt[e];
  if (mt * 128 >= M) return;
  const int Mrem = M - mt * 128;
  const int n0 = nt * 64;
  const int NT = 32;

  __shared__ __align__(16) unsigned short As[2][128][32];
  __shared__ __align__(16) unsigned short Bs[128][32];

  const int tid = threadIdx.x;
  const int lane = tid & 63;
  const int wid = tid >> 6;
  const int wm = (wid >> 1) * 64;
  const int wn = (wid & 1) * 32;

  const unsigned short* aSrc0;
  const unsigned short* aSrc1;
  {
    int cg = ((lane & 3) ^ ((lane >> 3) & 3)) * 8;
#pragma unroll
    for (int i = 0; i < 2; ++i) {
      int r = wid * 32 + i * 16 + (lane >> 2);
      int idx = mt * 128 + ((r < Mrem) ? r : 0);
      int p = plist[e * T_ + idx];
      const unsigned short* s = hs_bf + (size_t)(p >> 1) * H_ + cg;
      if (i == 0) aSrc0 = s; else aSrc1 = s;
    }
  }
  const int rb = wid * 32 + (lane >> 1);
  const int wrow = (rb < 64) ? (e * 2 * I_ + n0 + rb)
                             : (e * 2 * I_ + I_ + n0 + (rb - 64));
  const float* bSrc = w13 + (size_t)wrow * H_ + (lane & 1) * 16;
  const int fb = (rb >> 1) & 3;
  unsigned short* bDst0 = &Bs[rb][((((lane & 1) << 1) | 0) ^ fb) * 8];
  unsigned short* bDst1 = &Bs[rb][((((lane & 1) << 1) | 1) ^ fb) * 8];

  const int rda = ((lane >> 4) ^ ((lane >> 1) & 3)) * 8;  // frag col (A & B)
  const int l15 = lane & 15;

  f32x4 accg[4][2] = {};
  f32x4 accu[4][2] = {};

  // 2-deep B pipeline registers
  float4 bset[2][4];

#pragma unroll
  for (int j = 0; j < 4; ++j) bset[0][j] = *(const float4*)(bSrc + j * 4);
  GLOAD_LDS16(aSrc0, &As[0][wid * 32][0]);
  GLOAD_LDS16(aSrc1, &As[0][wid * 32 + 16][0]);
#pragma unroll
  for (int j = 0; j < 4; ++j) bset[1][j] = *(const float4*)(bSrc + 32 + j * 4);

#pragma unroll 2
  for (int kt = 0; kt < NT; ++kt) {
    const int s = kt & 1;
    // W1: wait Breg(kt). queue: Breg(kt)(4), A(kt)(2), Breg(kt+1)(4)
    if (kt + 1 < NT) asm volatile("s_waitcnt vmcnt(6)" ::: "memory");
    else             asm volatile("s_waitcnt vmcnt(2)" ::: "memory");
    {
      u16x8 lo, hi;
      lo[0] = f2bf(bset[s][0].x); lo[1] = f2bf(bset[s][0].y);
      lo[2] = f2bf(bset[s][0].z); lo[3] = f2bf(bset[s][0].w);
      lo[4] = f2bf(bset[s][1].x); lo[5] = f2bf(bset[s][1].y);
      lo[6] = f2bf(bset[s][1].z); lo[7] = f2bf(bset[s][1].w);
      hi[0] = f2bf(bset[s][2].x); hi[1] = f2bf(bset[s][2].y);
      hi[2] = f2bf(bset[s][2].z); hi[3] = f2bf(bset[s][2].w);
      hi[4] = f2bf(bset[s][3].x); hi[5] = f2bf(bset[s][3].y);
      hi[6] = f2bf(bset[s][3].z); hi[7] = f2bf(bset[s][3].w);
      *(u16x8*)bDst0 = lo;
      *(u16x8*)bDst1 = hi;
    }
    if (kt + 1 < NT) {
      GLOAD_LDS16(aSrc0 + (kt + 1) * 32, &As[s ^ 1][wid * 32][0]);
      GLOAD_LDS16(aSrc1 + (kt + 1) * 32, &As[s ^ 1][wid * 32 + 16][0]);
    }
    if (kt + 2 < NT) {
#pragma unroll
      for (int j = 0; j < 4; ++j)
        bset[s][j] = *(const float4*)(bSrc + (kt + 2) * 32 + j * 4);
    }
    // W2: wait A(kt).
    if (kt + 2 < NT)      asm volatile("s_waitcnt vmcnt(10)" ::: "memory");
    else if (kt + 1 < NT) asm volatile("s_waitcnt vmcnt(6)" ::: "memory");
    else                  asm volatile("s_waitcnt vmcnt(0)" ::: "memory");
    asm volatile("s_waitcnt lgkmcnt(0)" ::: "memory");
    __builtin_amdgcn_s_barrier();
    __builtin_amdgcn_sched_barrier(0);

    bf16x8 bg[2], bu[2];
#pragma unroll
    for (int ni = 0; ni < 2; ++ni) {
      bg[ni] = *(const bf16x8*)&Bs[wn + ni * 16 + l15][rda];
      bu[ni] = *(const bf16x8*)&Bs[64 + wn + ni * 16 + l15][rda];
    }
#pragma unroll
    for (int mi = 0; mi < 4; ++mi) {
      bf16x8 af = *(const bf16x8*)&As[s][wm + mi * 16 + l15][rda];
#pragma unroll
      for (int ni = 0; ni < 2; ++ni) {
        accg[mi][ni] = __builtin_amdgcn_mfma_f32_16x16x32_bf16(af, bg[ni], accg[mi][ni], 0, 0, 0);
        accu[mi][ni] = __builtin_amdgcn_mfma_f32_16x16x32_bf16(af, bu[ni], accu[mi][ni], 0, 0, 0);
      }
    }
    __builtin_amdgcn_sched_barrier(0);
    __builtin_amdgcn_s_barrier();
  }

  const int lrow = lane >> 4, lcol = lane & 15;
#pragma unroll
  for (int mi = 0; mi < 4; ++mi) {
#pragma unroll
    for (int r = 0; r < 4; ++r) {
      int rl = wm + mi * 16 + lrow * 4 + r;
      if (rl < Mrem) {
        int rr = mt * 128 + rl;
        int p = plist[e * T_ + rr];
        float w = wlist[e * T_ + rr];
        unsigned short* dst = act + (size_t)p * I_ + n0;
#pragma unroll
        for (int ni = 0; ni < 2; ++ni) {
          float g = accg[mi][ni][r];
          float u = accu[mi][ni][r];
          float a = (g / (1.f + __expf(-g))) * u * w;
          dst[wn + ni * 16 + lcol] = f2bf(a);
        }
      }
    }
  }
}

// ---------------- GEMM2: part[kb][p][h] = act[p,k0:+512].w2[e,h,k0:+512] ----
// BM=128, BN=128 h-cols, BK=32, K-split x4, non-temporal partial stores.
__global__ __launch_bounds__(256, 4) void gemm2_kernel(
    const unsigned short* __restrict__ act,
    const float* __restrict__ w2,
    const int* __restrict__ cnt, const int* __restrict__ plist,
    float* __restrict__ part) {
  const int bid = blockIdx.x;
  const int e = bid & 7;
  const int mt = (bid >> 3) & 15;
  const int nt = (bid >> 7) & 7;
  const int kb = bid >> 10;                // 0..3, K chunk of 512
  const int M = cnt[e];
  if (mt * 128 >= M) return;
  const int Mrem = M - mt * 128;
  const int n0 = nt * 128;
  const int k0 = kb * 512;

  __shared__ __align__(16) unsigned short As[2][128][32];
  __shared__ __align__(16) unsigned short Bs[128][32];

  const int tid = threadIdx.x;
  const int lane = tid & 63;
  const int wid = tid >> 6;
  const int wm = (wid >> 1) * 64;
  const int wn = (wid & 1) * 64;

  const unsigned short* aSrc0;
  const unsigned short* aSrc1;
  {
    int cg = ((lane & 3) ^ ((lane >> 3) & 3)) * 8;
#pragma unroll
    for (int i = 0; i < 2; ++i) {
      int r = wid * 32 + i * 16 + (lane >> 2);
      int idx = mt * 128 + ((r < Mrem) ? r : 0);
      int p = plist[e * T_ + idx];
      const unsigned short* s = act + (size_t)p * I_ + k0 + cg;
      if (i == 0) aSrc0 = s; else aSrc1 = s;
    }
  }
  const int rb = wid * 32 + (lane >> 1);
  const float* bSrc = w2 + ((size_t)e * H_ + n0 + rb) * I_ + k0 + (lane & 1) * 16;
  const int fb = (rb >> 1) & 3;
  unsigned short* bDst0 = &Bs[rb][((((lane & 1) << 1) | 0) ^ fb) * 8];
  unsigned short* bDst1 = &Bs[rb][((((lane & 1) << 1) | 1) ^ fb) * 8];

  const int rda = ((lane >> 4) ^ ((lane >> 1) & 3)) * 8;
  const int l15 = lane & 15;

  f32x4 acc[4][4] = {};

  GLOAD_LDS16(aSrc0, &As[0][wid * 32][0]);
  GLOAD_LDS16(aSrc1, &As[0][wid * 32 + 16][0]);
  float4 b0 = *(const float4*)(bSrc + 0);
  float4 b1 = *(const float4*)(bSrc + 4);
  float4 b2 = *(const float4*)(bSrc + 8);
  float4 b3 = *(const float4*)(bSrc + 12);

#pragma unroll 1
  for (int kt = 0; kt < 16; ++kt) {
    const int cur = kt & 1;
    asm volatile("s_waitcnt vmcnt(0)" ::: "memory");
    {
      u16x8 lo, hi;
      lo[0] = f2bf(b0.x); lo[1] = f2bf(b0.y); lo[2] = f2bf(b0.z); lo[3] = f2bf(b0.w);
      lo[4] = f2bf(b1.x); lo[5] = f2bf(b1.y); lo[6] = f2bf(b1.z); lo[7] = f2bf(b1.w);
      hi[0] = f2bf(b2.x); hi[1] = f2bf(b2.y); hi[2] = f2bf(b2.z); hi[3] = f2bf(b2.w);
      hi[4] = f2bf(b3.x); hi[5] = f2bf(b3.y); hi[6] = f2bf(b3.z); hi[7] = f2bf(b3.w);
      *(u16x8*)bDst0 = lo;
      *(u16x8*)bDst1 = hi;
    }
    if (kt + 1 < 16) {
      GLOAD_LDS16(aSrc0 + (kt + 1) * 32, &As[cur ^ 1][wid * 32][0]);
      GLOAD_LDS16(aSrc1 + (kt + 1) * 32, &As[cur ^ 1][wid * 32 + 16][0]);
      b0 = *(const float4*)(bSrc + (kt + 1) * 32 + 0);
      b1 = *(const float4*)(bSrc + (kt + 1) * 32 + 4);
      b2 = *(const float4*)(bSrc + (kt + 1) * 32 + 8);
      b3 = *(const float4*)(bSrc + (kt + 1) * 32 + 12);
    }
    asm volatile("s_waitcnt lgkmcnt(0)" ::: "memory");
    __builtin_amdgcn_s_barrier();
    __builtin_amdgcn_sched_barrier(0);

    bf16x8 bb[4];
#pragma unroll
    for (int ni = 0; ni < 4; ++ni)
      bb[ni] = *(const bf16x8*)&Bs[wn + ni * 16 + l15][rda];
#pragma unroll
    for (int mi = 0; mi < 4; ++mi) {
      bf16x8 af = *(const bf16x8*)&As[cur][wm + mi * 16 + l15][rda];
#pragma unroll
      for (int ni = 0; ni < 4; ++ni)
        acc[mi][ni] = __builtin_amdgcn_mfma_f32_16x16x32_bf16(af, bb[ni], acc[mi][ni], 0, 0, 0);
    }
    __builtin_amdgcn_sched_barrier(0);
    __builtin_amdgcn_s_barrier();
  }

  const int lrow = lane >> 4, lcol = lane & 15;
#pragma unroll
  for (int mi = 0; mi < 4; ++mi) {
#pragma unroll
    for (int r = 0; r < 4; ++r) {
      int rl = wm + mi * 16 + lrow * 4 + r;
      if (rl < Mrem) {
        int p = plist[e * T_ + mt * 128 + rl];
        float* dst = part + ((size_t)kb * 2 * T_ + p) * H_ + n0 + wn + lcol;
#pragma unroll
        for (int ni = 0; ni < 4; ++ni)
          __builtin_nontemporal_store(acc[mi][ni][r], dst + ni * 16);
      }
    }
  }
}

// ---------------- reduce: out[t,h] = sum_kb sum_pp part[kb][2t+pp][h] -------
__global__ __launch_bounds__(256) void reduce_kernel(const float* __restrict__ part,
                                                     float* __restrict__ out) {
  int i = blockIdx.x * blockDim.x + threadIdx.x;   // over T_*H_/4
  int t = i >> 8;                                  // H_/4 = 256
  int c = (i & 255) << 2;
  f32x4 s = {0.f, 0.f, 0.f, 0.f};
#pragma unroll
  for (int kb = 0; kb < 4; ++kb) {
#pragma unroll
    for (int pp = 0; pp < 2; ++pp) {
      f32x4 v = __builtin_nontemporal_load(
          (const f32x4*)(part + ((size_t)kb * 2 * T_ + 2 * t + pp) * H_ + c));
      s += v;
    }
  }
  *(f32x4*)(out + (size_t)t * H_ + c) = s;
}

extern "C" void kernel_launch(void* const* d_in, const int* in_sizes, int n_in,
                              void* d_out, int out_size, void* d_ws, size_t ws_size,
                              hipStream_t stream) {
  const float* hs     = (const float*)d_in[0];
  const float* logits = (const float*)d_in[1];
  const float* w13    = (const float*)d_in[2];
  const float* w2     = (const float*)d_in[3];
  float* out = (float*)d_out;

  char* ws = (char*)d_ws;
  size_t off = 0;
  int* cnt = (int*)(ws + off);           off += 256;
  int* plist = (int*)(ws + off);         off += (size_t)E_ * T_ * 4;
  float* wlist = (float*)(ws + off);     off += (size_t)E_ * T_ * 4;
  unsigned short* act = (unsigned short*)(ws + off);   off += (size_t)2 * T_ * I_ * 2;
  unsigned short* hs_bf = (unsigned short*)(ws + off); off += (size_t)T_ * H_ * 2;
  float* part = (float*)(ws + off);      off += (size_t)4 * 2 * T_ * H_ * 4;
  // total ~84 MB

  hipMemsetAsync(cnt, 0, 256, stream);

  const int nHs = T_ * H_ / 8;
  cvt_kernel<<<(nHs + 255) / 256, 256, 0, stream>>>(hs, hs_bf, nHs);
  router_kernel<<<T_ / 256, 256, 0, stream>>>(logits, cnt, plist, wlist);

  gemm1_kernel<<<E_ * 16 * 32, 256, 0, stream>>>(hs_bf, w13, cnt, plist, wlist, act);
  gemm2_kernel<<<E_ * 16 * 8 * 4, 256, 0, stream>>>(act, w2, cnt, plist, part);
  reduce_kernel<<<T_ * H_ / 4 / 256, 256, 0, stream>>>(part, out);
}

// Round 9
// 195.029 us; speedup vs baseline: 1.5181x; 1.3623x over previous
//
#include <hip/hip_runtime.h>

#define T_ 2048
#define H_ 1024
#define E_ 8
#define I_ 2048

typedef short bf16x8 __attribute__((ext_vector_type(8)));
typedef float f32x4 __attribute__((ext_vector_type(4)));
typedef unsigned short u16x8 __attribute__((ext_vector_type(8)));

__device__ __forceinline__ unsigned short f2bf(float f) {
  unsigned u = __builtin_bit_cast(unsigned, f);
  u += 0x7fffu + ((u >> 16) & 1u);   // RNE (finite inputs only)
  return (unsigned short)(u >> 16);
}

__device__ __forceinline__ float bf2f(unsigned short h) {
  unsigned u = ((unsigned)h) << 16;
  return __builtin_bit_cast(float, u);
}

#define GLOAD_LDS16(g, l)                                                     \
  __builtin_amdgcn_global_load_lds(                                           \
      (const __attribute__((address_space(1))) unsigned int*)(g),             \
      (__attribute__((address_space(3))) unsigned int*)(l), 16, 0, 0)

// ---------------- fp32 -> bf16 linear convert (hs only) --------------------
__global__ __launch_bounds__(256) void cvt_kernel(const float* __restrict__ s,
                                                  unsigned short* __restrict__ d,
                                                  int n8) {
  int i = blockIdx.x * blockDim.x + threadIdx.x;
  if (i >= n8) return;
  const float4* s4 = (const float4*)s;
  float4 a = s4[2 * i], b = s4[2 * i + 1];
  u16x8 v;
  v[0] = f2bf(a.x); v[1] = f2bf(a.y); v[2] = f2bf(a.z); v[3] = f2bf(a.w);
  v[4] = f2bf(b.x); v[5] = f2bf(b.y); v[6] = f2bf(b.z); v[7] = f2bf(b.w);
  *(u16x8*)(d + (size_t)i * 8) = v;
}

// ---------------- router: softmax + top2 + expert compaction ----------------
__global__ void router_kernel(const float* __restrict__ logits,
                              int* __restrict__ cnt,
                              int* __restrict__ plist,
                              float* __restrict__ wlist) {
  int t = blockIdx.x * blockDim.x + threadIdx.x;
  if (t >= T_) return;
  float l[E_];
#pragma unroll
  for (int e = 0; e < E_; ++e) l[e] = logits[t * E_ + e];
  int i0 = 0;
#pragma unroll
  for (int e = 1; e < E_; ++e) if (l[e] > l[i0]) i0 = e;
  int i1 = (i0 == 0) ? 1 : 0;
#pragma unroll
  for (int e = 0; e < E_; ++e) if (e != i0 && l[e] > l[i1]) i1 = e;
  float w1 = 1.f / (1.f + __expf(l[i0] - l[i1]));
  float w0 = 1.f - w1;
  int s0 = atomicAdd(&cnt[i0], 1);
  plist[i0 * T_ + s0] = 2 * t;
  wlist[i0 * T_ + s0] = w0;
  int s1 = atomicAdd(&cnt[i1], 1);
  plist[i1 * T_ + s1] = 2 * t + 1;
  wlist[i1 * T_ + s1] = w1;
}

// ---------------- GEMM1: act = silu(hs*w13_g)*(hs*w13_u)*w ------------------
// EXACT r5 structure (proven ~55us when L3 is unpolluted).
// BM=128, BN=64 i-cols (gate+up => 128 B rows), BK=32, 4 waves.
__global__ __launch_bounds__(256, 4) void gemm1_kernel(
    const unsigned short* __restrict__ hs_bf,
    const float* __restrict__ w13,
    const int* __restrict__ cnt, const int* __restrict__ plist,
    const float* __restrict__ wlist, unsigned short* __restrict__ act) {
  const int bid = blockIdx.x;
  const int e = bid & 7;
  const int mt = (bid >> 3) & 15;
  const int nt = bid >> 7;                 // 0..31
  const int M = cnt[e];
  if (mt * 128 >= M) return;
  const int Mrem = M - mt * 128;
  const int n0 = nt * 64;

  __shared__ __align__(16) unsigned short As[2][128][32];
  __shared__ __align__(16) unsigned short Bs[128][32];

  const int tid = threadIdx.x;
  const int lane = tid & 63;
  const int wid = tid >> 6;
  const int wm = (wid >> 1) * 64;
  const int wn = (wid & 1) * 32;

  const unsigned short* aSrc0;
  const unsigned short* aSrc1;
  {
    int cg = ((lane & 3) ^ ((lane >> 3) & 3)) * 8;
#pragma unroll
    for (int i = 0; i < 2; ++i) {
      int r = wid * 32 + i * 16 + (lane >> 2);
      int idx = mt * 128 + ((r < Mrem) ? r : 0);
      int p = plist[e * T_ + idx];
      const unsigned short* s = hs_bf + (size_t)(p >> 1) * H_ + cg;
      if (i == 0) aSrc0 = s; else aSrc1 = s;
    }
  }
  const int rb = wid * 32 + (lane >> 1);
  const int wrow = (rb < 64) ? (e * 2 * I_ + n0 + rb)
                             : (e * 2 * I_ + I_ + n0 + (rb - 64));
  const float* bSrc = w13 + (size_t)wrow * H_ + (lane & 1) * 16;
  const int fb = (rb >> 1) & 3;
  unsigned short* bDst0 = &Bs[rb][((((lane & 1) << 1) | 0) ^ fb) * 8];
  unsigned short* bDst1 = &Bs[rb][((((lane & 1) << 1) | 1) ^ fb) * 8];

  const int rda = ((lane >> 4) ^ ((lane >> 1) & 3)) * 8;  // frag col (A & B)
  const int l15 = lane & 15;

  f32x4 accg[4][2] = {};
  f32x4 accu[4][2] = {};

  GLOAD_LDS16(aSrc0, &As[0][wid * 32][0]);
  GLOAD_LDS16(aSrc1, &As[0][wid * 32 + 16][0]);
  float4 b0 = *(const float4*)(bSrc + 0);
  float4 b1 = *(const float4*)(bSrc + 4);
  float4 b2 = *(const float4*)(bSrc + 8);
  float4 b3 = *(const float4*)(bSrc + 12);

#pragma unroll 1
  for (int kt = 0; kt < 32; ++kt) {
    const int cur = kt & 1;
    asm volatile("s_waitcnt vmcnt(0)" ::: "memory");
    {
      u16x8 lo, hi;
      lo[0] = f2bf(b0.x); lo[1] = f2bf(b0.y); lo[2] = f2bf(b0.z); lo[3] = f2bf(b0.w);
      lo[4] = f2bf(b1.x); lo[5] = f2bf(b1.y); lo[6] = f2bf(b1.z); lo[7] = f2bf(b1.w);
      hi[0] = f2bf(b2.x); hi[1] = f2bf(b2.y); hi[2] = f2bf(b2.z); hi[3] = f2bf(b2.w);
      hi[4] = f2bf(b3.x); hi[5] = f2bf(b3.y); hi[6] = f2bf(b3.z); hi[7] = f2bf(b3.w);
      *(u16x8*)bDst0 = lo;
      *(u16x8*)bDst1 = hi;
    }
    if (kt + 1 < 32) {
      GLOAD_LDS16(aSrc0 + (kt + 1) * 32, &As[cur ^ 1][wid * 32][0]);
      GLOAD_LDS16(aSrc1 + (kt + 1) * 32, &As[cur ^ 1][wid * 32 + 16][0]);
      b0 = *(const float4*)(bSrc + (kt + 1) * 32 + 0);
      b1 = *(const float4*)(bSrc + (kt + 1) * 32 + 4);
      b2 = *(const float4*)(bSrc + (kt + 1) * 32 + 8);
      b3 = *(const float4*)(bSrc + (kt + 1) * 32 + 12);
    }
    asm volatile("s_waitcnt lgkmcnt(0)" ::: "memory");
    __builtin_amdgcn_s_barrier();
    __builtin_amdgcn_sched_barrier(0);

    bf16x8 bg[2], bu[2];
#pragma unroll
    for (int ni = 0; ni < 2; ++ni) {
      bg[ni] = *(const bf16x8*)&Bs[wn + ni * 16 + l15][rda];
      bu[ni] = *(const bf16x8*)&Bs[64 + wn + ni * 16 + l15][rda];
    }
#pragma unroll
    for (int mi = 0; mi < 4; ++mi) {
      bf16x8 af = *(const bf16x8*)&As[cur][wm + mi * 16 + l15][rda];
#pragma unroll
      for (int ni = 0; ni < 2; ++ni) {
        accg[mi][ni] = __builtin_amdgcn_mfma_f32_16x16x32_bf16(af, bg[ni], accg[mi][ni], 0, 0, 0);
        accu[mi][ni] = __builtin_amdgcn_mfma_f32_16x16x32_bf16(af, bu[ni], accu[mi][ni], 0, 0, 0);
      }
    }
    __builtin_amdgcn_sched_barrier(0);
    __builtin_amdgcn_s_barrier();
  }

  const int lrow = lane >> 4, lcol = lane & 15;
#pragma unroll
  for (int mi = 0; mi < 4; ++mi) {
#pragma unroll
    for (int r = 0; r < 4; ++r) {
      int rl = wm + mi * 16 + lrow * 4 + r;
      if (rl < Mrem) {
        int rr = mt * 128 + rl;
        int p = plist[e * T_ + rr];
        float w = wlist[e * T_ + rr];
        unsigned short* dst = act + (size_t)p * I_ + n0;
#pragma unroll
        for (int ni = 0; ni < 2; ++ni) {
          float g = accg[mi][ni][r];
          float u = accu[mi][ni][r];
          float a = (g / (1.f + __expf(-g))) * u * w;
          dst[wn + ni * 16 + lcol] = f2bf(a);
        }
      }
    }
  }
}

// ---------------- GEMM2: part[kb][p][h] = act[p,k0:+1024].w2[e,h,k0:+1024] --
// BM=128, BN=128 h-cols, BK=32, K-split x2, bf16 partials (16 MB total).
__global__ __launch_bounds__(256, 4) void gemm2_kernel(
    const unsigned short* __restrict__ act,
    const float* __restrict__ w2,
    const int* __restrict__ cnt, const int* __restrict__ plist,
    unsigned short* __restrict__ part) {
  const int bid = blockIdx.x;
  const int e = bid & 7;
  const int mt = (bid >> 3) & 15;
  const int nt = (bid >> 7) & 7;
  const int kb = bid >> 10;                // 0..1, K chunk of 1024
  const int M = cnt[e];
  if (mt * 128 >= M) return;
  const int Mrem = M - mt * 128;
  const int n0 = nt * 128;
  const int k0 = kb * 1024;

  __shared__ __align__(16) unsigned short As[2][128][32];
  __shared__ __align__(16) unsigned short Bs[128][32];

  const int tid = threadIdx.x;
  const int lane = tid & 63;
  const int wid = tid >> 6;
  const int wm = (wid >> 1) * 64;
  const int wn = (wid & 1) * 64;

  const unsigned short* aSrc0;
  const unsigned short* aSrc1;
  {
    int cg = ((lane & 3) ^ ((lane >> 3) & 3)) * 8;
#pragma unroll
    for (int i = 0; i < 2; ++i) {
      int r = wid * 32 + i * 16 + (lane >> 2);
      int idx = mt * 128 + ((r < Mrem) ? r : 0);
      int p = plist[e * T_ + idx];
      const unsigned short* s = act + (size_t)p * I_ + k0 + cg;
      if (i == 0) aSrc0 = s; else aSrc1 = s;
    }
  }
  const int rb = wid * 32 + (lane >> 1);
  const float* bSrc = w2 + ((size_t)e * H_ + n0 + rb) * I_ + k0 + (lane & 1) * 16;
  const int fb = (rb >> 1) & 3;
  unsigned short* bDst0 = &Bs[rb][((((lane & 1) << 1) | 0) ^ fb) * 8];
  unsigned short* bDst1 = &Bs[rb][((((lane & 1) << 1) | 1) ^ fb) * 8];

  const int rda = ((lane >> 4) ^ ((lane >> 1) & 3)) * 8;
  const int l15 = lane & 15;

  f32x4 acc[4][4] = {};

  GLOAD_LDS16(aSrc0, &As[0][wid * 32][0]);
  GLOAD_LDS16(aSrc1, &As[0][wid * 32 + 16][0]);
  float4 b0 = *(const float4*)(bSrc + 0);
  float4 b1 = *(const float4*)(bSrc + 4);
  float4 b2 = *(const float4*)(bSrc + 8);
  float4 b3 = *(const float4*)(bSrc + 12);

#pragma unroll 1
  for (int kt = 0; kt < 32; ++kt) {
    const int cur = kt & 1;
    asm volatile("s_waitcnt vmcnt(0)" ::: "memory");
    {
      u16x8 lo, hi;
      lo[0] = f2bf(b0.x); lo[1] = f2bf(b0.y); lo[2] = f2bf(b0.z); lo[3] = f2bf(b0.w);
      lo[4] = f2bf(b1.x); lo[5] = f2bf(b1.y); lo[6] = f2bf(b1.z); lo[7] = f2bf(b1.w);
      hi[0] = f2bf(b2.x); hi[1] = f2bf(b2.y); hi[2] = f2bf(b2.z); hi[3] = f2bf(b2.w);
      hi[4] = f2bf(b3.x); hi[5] = f2bf(b3.y); hi[6] = f2bf(b3.z); hi[7] = f2bf(b3.w);
      *(u16x8*)bDst0 = lo;
      *(u16x8*)bDst1 = hi;
    }
    if (kt + 1 < 32) {
      GLOAD_LDS16(aSrc0 + (kt + 1) * 32, &As[cur ^ 1][wid * 32][0]);
      GLOAD_LDS16(aSrc1 + (kt + 1) * 32, &As[cur ^ 1][wid * 32 + 16][0]);
      b0 = *(const float4*)(bSrc + (kt + 1) * 32 + 0);
      b1 = *(const float4*)(bSrc + (kt + 1) * 32 + 4);
      b2 = *(const float4*)(bSrc + (kt + 1) * 32 + 8);
      b3 = *(const float4*)(bSrc + (kt + 1) * 32 + 12);
    }
    asm volatile("s_waitcnt lgkmcnt(0)" ::: "memory");
    __builtin_amdgcn_s_barrier();
    __builtin_amdgcn_sched_barrier(0);

    bf16x8 bb[4];
#pragma unroll
    for (int ni = 0; ni < 4; ++ni)
      bb[ni] = *(const bf16x8*)&Bs[wn + ni * 16 + l15][rda];
#pragma unroll
    for (int mi = 0; mi < 4; ++mi) {
      bf16x8 af = *(const bf16x8*)&As[cur][wm + mi * 16 + l15][rda];
#pragma unroll
      for (int ni = 0; ni < 4; ++ni)
        acc[mi][ni] = __builtin_amdgcn_mfma_f32_16x16x32_bf16(af, bb[ni], acc[mi][ni], 0, 0, 0);
    }
    __builtin_amdgcn_sched_barrier(0);
    __builtin_amdgcn_s_barrier();
  }

  const int lrow = lane >> 4, lcol = lane & 15;
#pragma unroll
  for (int mi = 0; mi < 4; ++mi) {
#pragma unroll
    for (int r = 0; r < 4; ++r) {
      int rl = wm + mi * 16 + lrow * 4 + r;
      if (rl < Mrem) {
        int p = plist[e * T_ + mt * 128 + rl];
        unsigned short* dst = part + ((size_t)kb * 2 * T_ + p) * H_ + n0 + wn + lcol;
#pragma unroll
        for (int ni = 0; ni < 4; ++ni)
          dst[ni * 16] = f2bf(acc[mi][ni][r]);
      }
    }
  }
}

// ---------- reduce: out[t,h] = sum_{kb,pp} bf16 part[kb][2t+pp][h] ----------
__global__ __launch_bounds__(256) void reduce_kernel(const unsigned short* __restrict__ part,
                                                     float* __restrict__ out) {
  int i = blockIdx.x * blockDim.x + threadIdx.x;   // over T_*H_/8
  int t = i >> 7;                                  // H_/8 = 128
  int c = (i & 127) << 3;
  float s[8] = {0.f, 0.f, 0.f, 0.f, 0.f, 0.f, 0.f, 0.f};
#pragma unroll
  for (int kb = 0; kb < 2; ++kb) {
#pragma unroll
    for (int pp = 0; pp < 2; ++pp) {
      u16x8 v = *(const u16x8*)(part + ((size_t)kb * 2 * T_ + 2 * t + pp) * H_ + c);
#pragma unroll
      for (int j = 0; j < 8; ++j) s[j] += bf2f(v[j]);
    }
  }
  float* o = out + (size_t)t * H_ + c;
  *(f32x4*)o = *(f32x4*)&s[0];
  *(f32x4*)(o + 4) = *(f32x4*)&s[4];
}

extern "C" void kernel_launch(void* const* d_in, const int* in_sizes, int n_in,
                              void* d_out, int out_size, void* d_ws, size_t ws_size,
                              hipStream_t stream) {
  const float* hs     = (const float*)d_in[0];
  const float* logits = (const float*)d_in[1];
  const float* w13    = (const float*)d_in[2];
  const float* w2     = (const float*)d_in[3];
  float* out = (float*)d_out;

  char* ws = (char*)d_ws;
  size_t off = 0;
  int* cnt = (int*)(ws + off);           off += 256;
  int* plist = (int*)(ws + off);         off += (size_t)E_ * T_ * 4;
  float* wlist = (float*)(ws + off);     off += (size_t)E_ * T_ * 4;
  unsigned short* act = (unsigned short*)(ws + off);   off += (size_t)2 * T_ * I_ * 2;
  unsigned short* hs_bf = (unsigned short*)(ws + off); off += (size_t)T_ * H_ * 2;
  unsigned short* part = (unsigned short*)(ws + off);  off += (size_t)2 * 2 * T_ * H_ * 2;
  // total ~38 MB

  hipMemsetAsync(cnt, 0, 256, stream);

  const int nHs = T_ * H_ / 8;
  cvt_kernel<<<(nHs + 255) / 256, 256, 0, stream>>>(hs, hs_bf, nHs);
  router_kernel<<<T_ / 256, 256, 0, stream>>>(logits, cnt, plist, wlist);

  gemm1_kernel<<<E_ * 16 * 32, 256, 0, stream>>>(hs_bf, w13, cnt, plist, wlist, act);
  gemm2_kernel<<<E_ * 16 * 8 * 2, 256, 0, stream>>>(act, w2, cnt, plist, part);
  reduce_kernel<<<T_ * H_ / 8 / 256, 256, 0, stream>>>(part, out);
}